// Round 3
// baseline (403.261 us; speedup 1.0000x reference)
//
#include <hip/hip_runtime.h>
#include <hip/hip_bf16.h>
#include <cstddef>
#include <cstdint>

// ---------------- problem constants ----------------
#define M_TOK   16384      // 32*512 tokens
#define N_CODE  8192       // NUM_LATENTS
#define K_DIM   256        // LATENT_DIM
#define NSPLIT  4
#define BM      128
#define BN      256
#define BK      32
#define KSTEPS  (K_DIM / BK)                 // 8
#define TILES   ((N_CODE / NSPLIT) / BN)     // 8
#define TOTAL_STEPS (TILES * KSTEPS)         // 64
// step buffer layout (48 KB): [xh 8K][xl 8K][wh 16K][wl 16K]
#define STEP_BYTES 49152
#define XH_OFF 0
#define XL_OFF 8192
#define WH_OFF 16384
#define WL_OFF 32768

typedef short bf16x8 __attribute__((ext_vector_type(8)));  // 8 bf16 = 4 VGPRs
typedef float f32x4  __attribute__((ext_vector_type(4)));

__device__ __forceinline__ unsigned short f2bf_rne(float f) {
    unsigned u = __float_as_uint(f);
    unsigned r = u + 0x7FFFu + ((u >> 16) & 1u);
    return (unsigned short)(r >> 16);
}
__device__ __forceinline__ float bf2f(unsigned short h) {
    union { unsigned u; float f; } c; c.u = ((unsigned)h) << 16; return c.f;
}

__device__ __forceinline__ void gload16(const void* g, void* l) {
    __builtin_amdgcn_global_load_lds(
        (const __attribute__((address_space(1))) void*)g,
        (__attribute__((address_space(3))) void*)l, 16, 0, 0);
}

// ---------------- prep: bf16 hi/lo split + fp32 norms ----------------
__global__ void vq_prep(const float* __restrict__ x, const float* __restrict__ cb,
                        unsigned short* __restrict__ xh, unsigned short* __restrict__ xl,
                        unsigned short* __restrict__ wh, unsigned short* __restrict__ wl,
                        float* __restrict__ x2, float* __restrict__ w2) {
    int gt   = blockIdx.x * blockDim.x + threadIdx.x;
    int row  = gt >> 6;
    int lane = gt & 63;
    if (row >= M_TOK + N_CODE) return;
    const float* src; unsigned short *dh, *dl; float* dn;
    if (row < M_TOK) {
        src = x + (size_t)row * K_DIM;
        dh = xh + (size_t)row * K_DIM; dl = xl + (size_t)row * K_DIM; dn = x2 + row;
    } else {
        int r = row - M_TOK;
        src = cb + (size_t)r * K_DIM;
        dh = wh + (size_t)r * K_DIM; dl = wl + (size_t)r * K_DIM; dn = w2 + r;
    }
    float4 v = ((const float4*)src)[lane];
    unsigned short h0 = f2bf_rne(v.x), h1 = f2bf_rne(v.y);
    unsigned short h2 = f2bf_rne(v.z), h3 = f2bf_rne(v.w);
    unsigned short l0 = f2bf_rne(v.x - bf2f(h0)), l1 = f2bf_rne(v.y - bf2f(h1));
    unsigned short l2 = f2bf_rne(v.z - bf2f(h2)), l3 = f2bf_rne(v.w - bf2f(h3));
    ushort4 hv; hv.x = h0; hv.y = h1; hv.z = h2; hv.w = h3;
    ushort4 lv; lv.x = l0; lv.y = l1; lv.z = l2; lv.w = l3;
    ((ushort4*)dh)[lane] = hv;
    ((ushort4*)dl)[lane] = lv;
    float s = v.x*v.x + v.y*v.y + v.z*v.z + v.w*v.w;
    #pragma unroll
    for (int off = 32; off > 0; off >>= 1) s += __shfl_down(s, off);
    if (lane == 0) *dn = s;
}

// ---------------- main: single-barrier reg-dbuf pipelined 3-term MFMA GEMM + argmin ----------------
// R8: R7's two-barrier lockstep made all 8 waves burst ds_reads together (~1536 cyc LDS,
// matrix idle) then burst MFMAs together (~1863 cyc matrix, LDS idle). Fix: register
// fragment double-buffer. Per step (ONE barrier):
//   vmcnt(6)  -> retire own stage(s+1) loads (12 newer stay in flight, depth-3 LDS bufs)
//   s_barrier -> buf(s+1) globally visible; also proves all waves done reading buf(s)
//   issue: 16 ds_read frags(s+1)->FB  +  6 global_load_lds stage(s+3)->buf(s)
//   48 MFMA on FA (overlaps the reads/stage: different pipes, same wave)
//   lgkmcnt(0); sched_barrier; swap(FA,FB)
// All x2/w2 access routed through LDS (staged once in prologue with counted gload16) so
// ZERO compiler-scheduled global loads pollute the manual vmcnt accounting.
// MFMAs term-major (al*bh all, ah*bl all, ah*bh all): per-accumulator add order unchanged
// -> bit-exact scores vs R5/R6/R7 (absmax 0).
__global__ __launch_bounds__(512, 2)
void vq_main_mfma(const unsigned short* __restrict__ xh, const unsigned short* __restrict__ xl,
                  const unsigned short* __restrict__ wh, const unsigned short* __restrict__ wl,
                  const float* __restrict__ x2, const float* __restrict__ w2,
                  float* __restrict__ pminv, int* __restrict__ pmini) {
    __shared__ __align__(1024) char sb[3][STEP_BYTES];   // 144 KB
    __shared__ float x2s[BM];        // 512 B
    __shared__ float w2s[N_CODE/NSPLIT];  // 8 KB (this split's w2 slice)
    __shared__ float red_d[BM][4];
    __shared__ int   red_i[BM][4];

    // XCD-aware remap: split = xcd&3 keeps one 2 MB codebook slice L2-resident per XCD
    const int fid   = blockIdx.y * NSPLIT + blockIdx.x;
    const int xcd   = fid & 7;
    const int split = xcd & 3;
    const int mtile = ((xcd >> 2) << 6) + (fid >> 3);
    const int gm    = mtile * BM;

    const int tid   = threadIdx.x;
    const int w     = tid >> 6;              // wave 0..7
    const int lane  = tid & 63;
    const int wr    = w >> 2;                // row half (0/1)
    const int wc    = w & 3;                 // col quarter (0..3)
    const int quad  = lane >> 4;             // 0..3
    const int l15   = lane & 15;

    // staging constants (same swizzle relation as R6/R7, verified bit-exact):
    const int srow4 = lane >> 2;                       // 0..15
    const int sg    = (lane & 3) ^ ((lane >> 3) & 3);  // pre-swizzled global chunk

    const char* xhp = (const char*)xh;
    const char* xlp = (const char*)xl;
    const char* whp = (const char*)wh;
    const char* wlp = (const char*)wl;

    const size_t xg0 = (size_t)(gm + w*16 + srow4) * (K_DIM*2) + (size_t)sg*16;
    const size_t wg0 = (size_t)(w*32 + srow4) * (K_DIM*2) + (size_t)sg*16;
    const size_t wg1 = wg0 + (size_t)16 * (K_DIM*2);
    const unsigned lxu = (unsigned)w*1024;   // wave-uniform LDS bases (lane*16 implicit)
    const unsigned lwu = (unsigned)w*2048;

    auto stage = [&](int s, char* buf) {
        const size_t kb  = (size_t)(s & (KSTEPS-1)) * (BK*2);
        const size_t nbo = ((size_t)(split*(N_CODE/NSPLIT) + (s >> 3) * BN)) * (K_DIM*2);
        gload16(xhp + xg0 + kb,        buf + XH_OFF + lxu);
        gload16(xlp + xg0 + kb,        buf + XL_OFF + lxu);
        gload16(whp + nbo + wg0 + kb,  buf + WH_OFF + lwu);
        gload16(whp + nbo + wg1 + kb,  buf + WH_OFF + lwu + 1024);
        gload16(wlp + nbo + wg0 + kb,  buf + WL_OFF + lwu);
        gload16(wlp + nbo + wg1 + kb,  buf + WL_OFF + lwu + 1024);
    };

    // ---- prologue: stage w2 slice (1 load/thread), x2 block (wave0/lanes<32), bufs 0..2
    gload16((const char*)w2 + (size_t)split*(N_CODE/NSPLIT)*4 + (size_t)w*1024 + (size_t)lane*16,
            (char*)w2s + lxu);
    if (w == 0 && lane < 32)
        gload16((const char*)x2 + (size_t)gm*4 + (size_t)lane*16, (char*)x2s);
    char* cur = &sb[0][0];
    char* nxt = &sb[1][0];
    char* bfar = &sb[2][0];
    stage(0, cur); stage(1, nxt); stage(2, bfar);
    // outstanding: w2(1) [+x2(1) wave0] + 18 stage -> vmcnt(12) retires w2,(x2),stage(0)
    asm volatile("s_waitcnt vmcnt(12)" ::: "memory");
    __builtin_amdgcn_s_barrier();
    __builtin_amdgcn_sched_barrier(0);

    const int slb = (quad ^ ((l15 >> 1) & 3)) * 16;   // swizzled read slot byte offset

    // frag register double-buffer
    bf16x8 ah0[4], al0[4], bh0[4], bl0[4];
    bf16x8 ah1[4], al1[4], bh1[4], bl1[4];

    // read frags(0) into set0
    #pragma unroll
    for (int rt = 0; rt < 4; ++rt) {
        const int off = (wr*64 + rt*16 + l15)*(BK*2) + slb;
        ah0[rt] = *(const bf16x8*)(cur + XH_OFF + off);
        al0[rt] = *(const bf16x8*)(cur + XL_OFF + off);
    }
    #pragma unroll
    for (int ct = 0; ct < 4; ++ct) {
        const int off = (wc*64 + ct*16 + l15)*(BK*2) + slb;
        bh0[ct] = *(const bf16x8*)(cur + WH_OFF + off);
        bl0[ct] = *(const bf16x8*)(cur + WL_OFF + off);
    }
    asm volatile("s_waitcnt lgkmcnt(0)" ::: "memory");
    __builtin_amdgcn_sched_barrier(0);

    float minv[16];
    int   mini[16];
    #pragma unroll
    for (int i = 0; i < 16; ++i) { minv[i] = 3.4e38f; mini[i] = 0; }

    f32x4 acc[4][4];

#define ITER(TILE, KCS, AHc, ALc, BHc, BLc, AHl, ALl, BHl, BLl)                       \
    do {                                                                              \
        const int step_ = (TILE)*KSTEPS + (KCS);                                      \
        if (step_ < TOTAL_STEPS-2) { asm volatile("s_waitcnt vmcnt(6)" ::: "memory"); } \
        else                       { asm volatile("s_waitcnt vmcnt(0)" ::: "memory"); } \
        __builtin_amdgcn_s_barrier();                                                 \
        __builtin_amdgcn_sched_barrier(0);                                            \
        if ((TILE) != TILES-1 || (KCS) != KSTEPS-1) {                                 \
            _Pragma("unroll")                                                         \
            for (int rt = 0; rt < 4; ++rt) {                                          \
                const int off_ = (wr*64 + rt*16 + l15)*(BK*2) + slb;                  \
                AHl[rt] = *(const bf16x8*)(nxt + XH_OFF + off_);                      \
                ALl[rt] = *(const bf16x8*)(nxt + XL_OFF + off_);                      \
            }                                                                         \
            _Pragma("unroll")                                                         \
            for (int ct = 0; ct < 4; ++ct) {                                          \
                const int off_ = (wc*64 + ct*16 + l15)*(BK*2) + slb;                  \
                BHl[ct] = *(const bf16x8*)(nxt + WH_OFF + off_);                      \
                BLl[ct] = *(const bf16x8*)(nxt + WL_OFF + off_);                      \
            }                                                                         \
        }                                                                             \
        if (step_ <= TOTAL_STEPS-4) stage(step_+3, cur);                              \
        __builtin_amdgcn_sched_barrier(0);                                            \
        __builtin_amdgcn_s_setprio(1);                                                \
        _Pragma("unroll")                                                             \
        for (int rt = 0; rt < 4; ++rt)                                                \
            _Pragma("unroll")                                                         \
            for (int ct = 0; ct < 4; ++ct)                                            \
                acc[rt][ct] = __builtin_amdgcn_mfma_f32_16x16x32_bf16(ALc[rt], BHc[ct], acc[rt][ct], 0, 0, 0); \
        _Pragma("unroll")                                                             \
        for (int rt = 0; rt < 4; ++rt)                                                \
            _Pragma("unroll")                                                         \
            for (int ct = 0; ct < 4; ++ct)                                            \
                acc[rt][ct] = __builtin_amdgcn_mfma_f32_16x16x32_bf16(AHc[rt], BLc[ct], acc[rt][ct], 0, 0, 0); \
        _Pragma("unroll")                                                             \
        for (int rt = 0; rt < 4; ++rt)                                                \
            _Pragma("unroll")                                                         \
            for (int ct = 0; ct < 4; ++ct)                                            \
                acc[rt][ct] = __builtin_amdgcn_mfma_f32_16x16x32_bf16(AHc[rt], BHc[ct], acc[rt][ct], 0, 0, 0); \
        __builtin_amdgcn_s_setprio(0);                                                \
        asm volatile("s_waitcnt lgkmcnt(0)" ::: "memory");                            \
        __builtin_amdgcn_sched_barrier(0);                                            \
        { char* t_ = cur; cur = nxt; nxt = bfar; bfar = t_; }                         \
    } while (0)

    for (int tile = 0; tile < TILES; ++tile) {
        #pragma unroll
        for (int rt = 0; rt < 4; ++rt)
            #pragma unroll
            for (int ct = 0; ct < 4; ++ct)
                acc[rt][ct] = (f32x4){0.f, 0.f, 0.f, 0.f};

        ITER(tile, 0, ah0, al0, bh0, bl0, ah1, al1, bh1, bl1);
        ITER(tile, 1, ah1, al1, bh1, bl1, ah0, al0, bh0, bl0);
        ITER(tile, 2, ah0, al0, bh0, bl0, ah1, al1, bh1, bl1);
        ITER(tile, 3, ah1, al1, bh1, bl1, ah0, al0, bh0, bl0);
        ITER(tile, 4, ah0, al0, bh0, bl0, ah1, al1, bh1, bl1);
        ITER(tile, 5, ah1, al1, bh1, bl1, ah0, al0, bh0, bl0);
        ITER(tile, 6, ah0, al0, bh0, bl0, ah1, al1, bh1, bl1);
        ITER(tile, 7, ah1, al1, bh1, bl1, ah0, al0, bh0, bl0);

        // ---- tile epilogue: argmin update (x2/w2 from LDS; no vmcnt pollution) ----
        const int nb = split * (N_CODE / NSPLIT) + tile * BN;
        f32x4 x2v[4];
        #pragma unroll
        for (int rt = 0; rt < 4; ++rt)
            x2v[rt] = *(const f32x4*)((const char*)x2s + (wr*64 + rt*16 + quad*4)*4);
        float w2c[4];
        int   cidx[4];
        #pragma unroll
        for (int ct = 0; ct < 4; ++ct) {
            cidx[ct] = nb + wc*64 + ct*16 + l15;
            w2c[ct]  = w2s[tile*BN + wc*64 + ct*16 + l15];
        }
        asm volatile("s_waitcnt lgkmcnt(0)" ::: "memory");
        #pragma unroll
        for (int rt = 0; rt < 4; ++rt)
            #pragma unroll
            for (int ct = 0; ct < 4; ++ct) {
                #pragma unroll
                for (int reg = 0; reg < 4; ++reg) {
                    float d = (x2v[rt][reg] - 2.0f * acc[rt][ct][reg]) + w2c[ct];
                    int r16 = rt*4 + reg;
                    if (d < minv[r16]) { minv[r16] = d; mini[r16] = cidx[ct]; }
                }
            }
    }
#undef ITER

    // reduce across the 16 lanes (same rows, different cols); tie-break lower index
    #pragma unroll
    for (int r16 = 0; r16 < 16; ++r16) {
        float d  = minv[r16];
        int   ix = mini[r16];
        #pragma unroll
        for (int off = 1; off < 16; off <<= 1) {
            float od = __shfl_xor(d, off);
            int   oi = __shfl_xor(ix, off);
            if (od < d || (od == d && oi < ix)) { d = od; ix = oi; }
        }
        if (l15 == 0) {
            int row_local = wr*64 + (r16 >> 2)*16 + quad*4 + (r16 & 3);
            red_d[row_local][wc] = d;
            red_i[row_local][wc] = ix;
        }
    }
    __syncthreads();
    // combine the four col-quarters, write per-split partials
    if (tid < BM) {
        float d  = red_d[tid][0];
        int   ix = red_i[tid][0];
        #pragma unroll
        for (int j = 1; j < 4; ++j) {
            float dj = red_d[tid][j];
            int   ij = red_i[tid][j];
            if (dj < d || (dj == d && ij < ix)) { d = dj; ix = ij; }
        }
        pminv[(size_t)(gm + tid) * NSPLIT + split] = d;
        pmini[(size_t)(gm + tid) * NSPLIT + split] = ix;
    }
}

// ---------------- epilogue: reduce NSPLIT partials in-wave, then z_q/z/x/indices ----------------
__global__ void vq_gather(const float* __restrict__ x, const float* __restrict__ cb,
                          const float* __restrict__ pminv, const int* __restrict__ pmini,
                          float* __restrict__ out) {
    int t = blockIdx.x * blockDim.x + threadIdx.x;   // float4 units
    int m = t >> 6;
    int q = t & 63;        // == lane: one wave handles exactly one row

    // NSPLIT-way split reduce, replicated across lanes via xor shuffles
    float d  = pminv[(size_t)m * NSPLIT + (q & (NSPLIT-1))];
    int   ix = pmini[(size_t)m * NSPLIT + (q & (NSPLIT-1))];
    #pragma unroll
    for (int off = 1; off < NSPLIT; off <<= 1) {
        float od = __shfl_xor(d, off);
        int   oi = __shfl_xor(ix, off);
        if (od < d || (od == d && oi < ix)) { d = od; ix = oi; }
    }

    float4 xv = ((const float4*)x)[t];
    float4 zv = ((const float4*)cb)[(size_t)ix * 64 + q];
    float4 zq;
    zq.x = xv.x + (zv.x - xv.x);
    zq.y = xv.y + (zv.y - xv.y);
    zq.z = xv.z + (zv.z - xv.z);
    zq.w = xv.w + (zv.w - xv.w);
    float4* o = (float4*)out;
    const int ELEM4 = M_TOK * 64;
    o[t]           = zq;     // z_q
    o[t + ELEM4]   = zv;     // z
    o[t + 2*ELEM4] = xv;     // x
    if (q == 0) out[(size_t)3 * M_TOK * K_DIM + m] = (float)ix;
}

// ---------------- launcher ----------------
extern "C" void kernel_launch(void* const* d_in, const int* in_sizes, int n_in,
                              void* d_out, int out_size, void* d_ws, size_t ws_size,
                              hipStream_t stream) {
    const float* x  = (const float*)d_in[0];   // 16384 x 256
    const float* cb = (const float*)d_in[1];   // 8192 x 256
    float* out = (float*)d_out;

    // workspace layout
    char* p = (char*)d_ws;
    unsigned short* xh = (unsigned short*)p;  p += (size_t)M_TOK  * K_DIM * 2;  // 8 MB
    unsigned short* xl = (unsigned short*)p;  p += (size_t)M_TOK  * K_DIM * 2;  // 8 MB
    unsigned short* wh = (unsigned short*)p;  p += (size_t)N_CODE * K_DIM * 2;  // 4 MB
    unsigned short* wl = (unsigned short*)p;  p += (size_t)N_CODE * K_DIM * 2;  // 4 MB
    float* x2    = (float*)p;  p += (size_t)M_TOK * 4;
    float* w2    = (float*)p;  p += (size_t)N_CODE * 4;
    float* pminv = (float*)p;  p += (size_t)M_TOK * NSPLIT * 4;
    int*   pmini = (int*)p;    p += (size_t)M_TOK * NSPLIT * 4;

    // prep: one wave per row, 24576 rows
    {
        int waves = M_TOK + N_CODE;
        vq_prep<<<(waves * 64 + 255) / 256, 256, 0, stream>>>(x, cb, xh, xl, wh, wl, x2, w2);
    }
    // main fused MFMA GEMM + argmin (single-barrier reg-dbuf pipeline)
    {
        dim3 grid(NSPLIT, M_TOK / BM);   // 4 x 128 = 512 blocks
        vq_main_mfma<<<grid, 512, 0, stream>>>(xh, xl, wh, wl, x2, w2, pminv, pmini);
    }
    // epilogue (split-reduce fused in)
    {
        int t = M_TOK * (K_DIM / 4);     // 1048576 float4 threads
        vq_gather<<<t / 256, 256, 0, stream>>>(x, cb, pminv, pmini, out);
    }
}